// Round 1
// baseline (17229.240 us; speedup 1.0000x reference)
//
#include <hip/hip_runtime.h>

#define T_STEPS 1000
#define BATCH   256
#define NIN     128
#define NHID    512
#define NOUT    128
#define NBLK    16
#define ROWS    16   // batch rows per block (16 blocks x 16 = 256)

typedef _Float16 half8   __attribute__((ext_vector_type(8)));
typedef float    floatx4 __attribute__((ext_vector_type(4)));

__device__ __forceinline__ half8 f8_to_h8(const float* __restrict__ p) {
  floatx4 lo = *(const floatx4*)p;
  floatx4 hi = *(const floatx4*)(p + 4);
  half8 r;
#pragma unroll
  for (int i = 0; i < 4; ++i) { r[i] = (_Float16)lo[i]; r[i + 4] = (_Float16)hi[i]; }
  return r;
}

// ---------------------------------------------------------------------------
// Workspace stream region: 512 frags x 1 KiB = 512 KiB of fp16 weight
// fragments in MFMA-B operand order, so each stream load is one coalesced
// 1 KiB global_load_dwordx4 per wave. Per wave w (0..7), 64 frags:
//   f in [0,16):  Win  frags, tt=f>>2, kk=f&3        (K-chunks 0..3 of NIN)
//   f in [16,48): Wrec frags, i=f-16, tt=i>>3, kk=(i&7)+8  (K-chunks 8..15)
//   f in [48,64): Wout frags, kk=f-48                (K-chunks 0..15)
// B-frag layout (mfma_f32_16x16x32_f16): lane l holds W[col0+(l&15)][k0+(l>>4)*8+j]
// ---------------------------------------------------------------------------
__global__ void prep_weights_kernel(const float* __restrict__ Win,
                                    const float* __restrict__ Wrec,
                                    const float* __restrict__ Wout,
                                    _Float16* __restrict__ wsf) {
  const int fid  = blockIdx.x;    // 0..511
  const int lane = threadIdx.x;   // 0..63
  const int w  = fid >> 6;
  const int f  = fid & 63;
  const int lr = lane & 15, lq = lane >> 4;
  const float* src; int col, K, k0;
  if (f < 16)      { int tt = f >> 2, kk = f & 3;
                     src = Win;  K = NIN;  col = w*64 + tt*16 + lr; k0 = kk*32 + lq*8; }
  else if (f < 48) { int i = f - 16; int tt = i >> 3, kk = (i & 7) + 8;
                     src = Wrec; K = NHID; col = w*64 + tt*16 + lr; k0 = kk*32 + lq*8; }
  else             { int kk = f - 48;
                     src = Wout; K = NHID; col = w*16 + lr;         k0 = kk*32 + lq*8; }
  half8 v = f8_to_h8(src + (size_t)col * K + k0);
  *(half8*)(wsf + ((size_t)fid * 64 + lane) * 8) = v;
}

// ---------------------------------------------------------------------------
// LDS map (bytes), 147456 total:
//   [0, 131072)       Wrec LDS-resident: 128 frags of 1 KiB (w, kk-4 in 0..3, tt)
//   [131072, 147456)  s_lds: 16 rows x 512 cols fp16, row stride 1024 B,
//                     XOR-swizzled: byte ^= ((row&7)<<4)  (breaks the 16-way
//                     bank conflict of stride-1024 column reads; 2B scatter
//                     writes land 2-way = free)
// ---------------------------------------------------------------------------
#define WLDS_OFF(w, kkl, tt) ((((w)*16 + (kkl)*4 + (tt)) * 64) * 16)
#define S_OFF   131072
#define SROW    1024
#define SADDR(row, kb) (S_OFF + (row)*SROW + ((kb) ^ (((row)&7)<<4)))

__global__ __launch_bounds__(512, 2) void bnn_lds_kernel(
    const float* __restrict__ X,     // [T,B,NIN]
    const float* __restrict__ Wrec,  // [NHID,NHID] f32
    const float* __restrict__ bin,   // [NHID]
    const float* __restrict__ bout,  // [NOUT]
    float* __restrict__ out,         // [T,B,NOUT]
    const _Float16* __restrict__ wsf)
{
  __shared__ __attribute__((aligned(16))) char smem[147456];
  const int tid = threadIdx.x;
  const int l   = tid & 63;
  const int w   = tid >> 6;          // wave 0..7: hidden cols [w*64, +64), out cols [w*16, +16)
  const int lr  = l & 15;
  const int lq  = l >> 4;
  const int cw  = w * 64;
  const int m0  = blockIdx.x * ROWS; // this block's batch rows

  // ---- zero s_lds (s_{-1} = 0): 512 thr x 32 B ----
  *(int4*)(smem + S_OFF + tid * 32)      = make_int4(0, 0, 0, 0);
  *(int4*)(smem + S_OFF + tid * 32 + 16) = make_int4(0, 0, 0, 0);

  // ---- VGPR-resident Wrec K-chunks 0..3 (64 VGPR/wave) ----
  half8 wr[4][4];
#pragma unroll
  for (int tt = 0; tt < 4; ++tt)
#pragma unroll
    for (int kk = 0; kk < 4; ++kk)
      wr[tt][kk] = f8_to_h8(Wrec + (size_t)(cw + tt*16 + lr) * NHID + kk*32 + lq*8);

  // ---- LDS-resident Wrec K-chunks 4..7 (128 KiB, frag order, own wave only) ----
#pragma unroll
  for (int kk = 0; kk < 4; ++kk)
#pragma unroll
    for (int tt = 0; tt < 4; ++tt) {
      half8 v = f8_to_h8(Wrec + (size_t)(cw + tt*16 + lr) * NHID + (kk + 4)*32 + lq*8);
      *(half8*)(smem + WLDS_OFF(w, kk, tt) + l * 16) = v;
    }

  float binv[4];
#pragma unroll
  for (int tt = 0; tt < 4; ++tt) binv[tt] = bin[cw + tt*16 + lr];
  const float bo = bout[w*16 + lr];
  const _Float16* wst = wsf + (size_t)w * 64 * 512;  // this wave's 64 stream frags

  // ---- GLIFR state in registers: element (row = lq*4+r, col = cw+tt*16+lr) ----
  float v[16], a0[16], a1[16], sp[16];
#pragma unroll
  for (int i = 0; i < 16; ++i) { v[i] = 0.f; a0[i] = 0.f; a1[i] = 0.f; sp[i] = 0.f; }

  const float C_VI = (float)(0.05 * 0.2 * (0.1 + 1.0 / 512.0));  // DT*K_M*R_HID

  __syncthreads();   // s_lds zero + wrec_lds fill visible

#pragma unroll 1
  for (int t = 0; t <= T_STEPS; ++t) {
    // ---- issue X loads early (consumed after the 80-MFMA recurrence) ----
    floatx4 xlo[4], xhi[4];
    if (t < T_STEPS) {
      const float* xt = X + (size_t)t * (BATCH * NIN) + (size_t)(m0 + lr) * NIN + lq * 8;
#pragma unroll
      for (int kk = 0; kk < 4; ++kk) {
        xlo[kk] = *(const floatx4*)(xt + kk * 32);
        xhi[kk] = *(const floatx4*)(xt + kk * 32 + 4);
      }
    }

    floatx4 acc[4], ro;
#pragma unroll
    for (int tt = 0; tt < 4; ++tt) {
      acc[tt][0] = binv[tt]; acc[tt][1] = binv[tt];
      acc[tt][2] = binv[tt]; acc[tt][3] = binv[tt];
    }
    ro[0] = bo; ro[1] = bo; ro[2] = bo; ro[3] = bo;

    // ---- recurrence (s_{t-1} @ Wrec.T) + readout (s_{t-1} @ Wout.T), K=512 ----
    // A-frags (s_prev) read ONCE from s_lds and shared by both products.
#pragma unroll
    for (int kk = 0; kk < 16; ++kk) {
      half8 as  = *(const half8*)(smem + SADDR(lr, kk*64 + lq*16));
      half8 wof = *(const half8*)(wst + (48 + kk) * 512 + l * 8);            // Wout stream
      ro = __builtin_amdgcn_mfma_f32_16x16x32_f16(as, wof, ro, 0, 0, 0);
      if (t < T_STEPS) {
#pragma unroll
        for (int tt = 0; tt < 4; ++tt) {
          half8 wb;
          if (kk < 4)       wb = wr[tt][kk];                                  // VGPR
          else if (kk < 8)  wb = *(const half8*)(smem + WLDS_OFF(w, kk - 4, tt) + l * 16); // LDS
          else              wb = *(const half8*)(wst + (16 + tt*8 + (kk - 8)) * 512 + l * 8); // L2 stream
          acc[tt] = __builtin_amdgcn_mfma_f32_16x16x32_f16(as, wb, acc[tt], 0, 0, 0);
        }
      }
    }

    // ---- input projection x_t @ Win.T (streamed Win frags) ----
    if (t < T_STEPS) {
#pragma unroll
      for (int kk = 0; kk < 4; ++kk) {
        half8 xa;
#pragma unroll
        for (int i = 0; i < 4; ++i) {
          xa[i]     = (_Float16)xlo[kk][i];
          xa[i + 4] = (_Float16)xhi[kk][i];
        }
#pragma unroll
        for (int tt = 0; tt < 4; ++tt) {
          half8 wif = *(const half8*)(wst + (tt*4 + kk) * 512 + l * 8);
          acc[tt] = __builtin_amdgcn_mfma_f32_16x16x32_f16(xa, wif, acc[tt], 0, 0, 0);
        }
      }
    }

    __syncthreads();   // all waves done reading s_{t-1} from s_lds

    // ---- GLIFR pointwise update; scatter s_t into s_lds (swizzled) ----
    if (t < T_STEPS) {
#pragma unroll
      for (int tt = 0; tt < 4; ++tt)
#pragma unroll
        for (int r = 0; r < 4; ++r) {
          const int i = tt*4 + r;
          const float y  = 0.5f * acc[tt][r];                 // avg of the 2 inputs
          a0[i] = a0[i] * 0.85f - 0.05f * sp[i];              // 1-DT*3,  DT*1*(-1)
          a1[i] = a1[i] * -0.5f - 0.05f * sp[i];              // 1-DT*30, DT*(-1)*1
          const float it = y + a0[i] + a1[i] + 700.0f;        // + I0
          v[i] = v[i] * 0.99f * (1.0f - 0.05f * sp[i]) + C_VI * it;
          const float s = 20.0f / (1.0f + __expf(-0.02f * v[i]));  // 20*sigmoid(v/50)
          sp[i] = s;
          const int row = lq*4 + r;                           // C/D: row=(l>>4)*4+reg
          *(_Float16*)(smem + SADDR(row, (cw + tt*16 + lr) * 2)) = (_Float16)s;
        }
    }

    __syncthreads();   // s_t visible to all waves for next step

    // ---- store out[t-1] = s_{t-1} @ Wout.T + bout (fire-and-forget) ----
    if (t >= 1) {
      float* op = out + ((size_t)(t - 1) * BATCH + (m0 + lq*4)) * NOUT + w*16 + lr;
#pragma unroll
      for (int r = 0; r < 4; ++r) op[(size_t)r * NOUT] = ro[r];
    }
  }
}

extern "C" void kernel_launch(void* const* d_in, const int* in_sizes, int n_in,
                              void* d_out, int out_size, void* d_ws, size_t ws_size,
                              hipStream_t stream) {
  const float* X    = (const float*)d_in[0];
  const float* Win  = (const float*)d_in[1];
  const float* bin  = (const float*)d_in[2];
  const float* Wrec = (const float*)d_in[3];
  const float* Wout = (const float*)d_in[4];
  const float* bout = (const float*)d_in[5];
  float* out = (float*)d_out;
  _Float16* wsf = (_Float16*)d_ws;   // 512 KiB stream region (<= prior session's ws use)

  hipLaunchKernelGGL(prep_weights_kernel, dim3(512), dim3(64), 0, stream,
                     Win, Wrec, Wout, wsf);
  hipLaunchKernelGGL(bnn_lds_kernel, dim3(NBLK), dim3(512), 0, stream,
                     X, Wrec, bin, bout, out, wsf);
}

// Round 2
// 9235.883 us; speedup vs baseline: 1.8655x; 1.8655x over previous
//
#include <hip/hip_runtime.h>

#define T_STEPS 1000
#define BATCH   256
#define NIN     128
#define NHID    512
#define NOUT    128
#define ROWS    16    // batch rows per cluster
#define HGRP    4     // hidden groups (blocks per cluster)
#define HCOLS   128   // hidden cols per block
#define NCLU    16    // clusters
#define CLUSZ   4     // blocks per cluster

typedef _Float16 half8   __attribute__((ext_vector_type(8)));
typedef float    floatx4 __attribute__((ext_vector_type(4)));

__device__ __forceinline__ half8 f8_to_h8(const float* __restrict__ p) {
  floatx4 lo = *(const floatx4*)p;
  floatx4 hi = *(const floatx4*)(p + 4);
  half8 r;
#pragma unroll
  for (int i = 0; i < 4; ++i) { r[i] = (_Float16)lo[i]; r[i + 4] = (_Float16)hi[i]; }
  return r;
}

// ---------------------------------------------------------------------------
// Workspace layout (total 525312 B, same footprint as the round-0 kernel):
//   [0, 1024)           16 cluster barrier counters, 64 B apart
//   [1024, 1024+512K)   s exchange: 2 slots x 16 clusters x 16 KiB.
//     Slot s, cluster bi, halves base = s*131072 + bi*8192.
//     Within a cluster region: 16 A-frags of 1 KiB (frag kk covers hidden cols
//     [kk*32, kk*32+32) for the cluster's 16 batch rows). A-frag layout for
//     mfma_f32_16x16x32_f16: lane l holds s[row=l&15][k=kk*32+(l>>4)*8+j],
//     half index = kk*512 + l*8 + j.  Block (bi,hj) produces frags hj*4..hj*4+3.
// ---------------------------------------------------------------------------
#define EX_OFF 1024

__global__ void init_ws_kernel(char* __restrict__ ws) {
  size_t idx = (size_t)blockIdx.x * blockDim.x + threadIdx.x;  // 128*256 = 32768
  ((int4*)(ws + EX_OFF))[idx] = make_int4(0, 0, 0, 0);         // 32768*16 B = 512 KiB
  if (blockIdx.x == 0 && threadIdx.x < NCLU)
    *(unsigned int*)(ws + threadIdx.x * 64) = 0u;
}

// ---------------------------------------------------------------------------
// 64 blocks x 256 threads. bid = hj*16 + bi  (cluster {bi, bi+16, bi+32, bi+48}
// shares bid%8 -> same XCD under round-robin placement: perf heuristic only).
// LDS: [0,131072) Wrec B-frags: ((w*2+tt)*16+kk)*1024 + l*16  (linear, no conflicts)
//      [131072,135168) readout split-K partials, double-buffered by parity.
// ---------------------------------------------------------------------------
#define PBUF 131072

__global__ __launch_bounds__(256, 1) void bnn_cluster_kernel(
    const float* __restrict__ X,     // [T,B,NIN]
    const float* __restrict__ Win,   // [NHID,NIN]
    const float* __restrict__ bin,   // [NHID]
    const float* __restrict__ Wrec,  // [NHID,NHID]
    const float* __restrict__ Wout,  // [NOUT,NHID]
    const float* __restrict__ bout,  // [NOUT]
    float* __restrict__ out,         // [T,B,NOUT]
    char* __restrict__ ws)
{
  __shared__ __attribute__((aligned(16))) char smem[135168];
  const int tid = threadIdx.x;
  const int l   = tid & 63;
  const int w   = tid >> 6;          // wave 0..3
  const int lr  = l & 15;
  const int lq  = l >> 4;
  const int bi  = blockIdx.x & 15;   // cluster (batch group)
  const int hj  = blockIdx.x >> 4;   // hidden group
  const int m0  = bi * ROWS;
  const int cw  = hj * HCOLS + w * 32;  // this wave's 2 hidden tiles
  const int oj  = hj * 32;              // block's 32 out cols
  const int tw  = w & 1;                // readout tile (0/1)
  const int kh  = w >> 1;               // readout K-half (0/1)

  unsigned int* cnt = (unsigned int*)(ws + (size_t)bi * 64);
  _Float16* ex = (_Float16*)(ws + EX_OFF);

  // ---- one-time: Wrec B-frags -> LDS (fp16, fragment order) ----
#pragma unroll
  for (int tt = 0; tt < 2; ++tt)
#pragma unroll
    for (int kk = 0; kk < 16; ++kk) {
      half8 v = f8_to_h8(Wrec + (size_t)(cw + tt*16 + lr) * NHID + kk*32 + lq*8);
      *(half8*)(smem + (((w*2 + tt)*16 + kk) * 64 + l) * 16) = v;
    }

  // ---- VGPR-resident Win frags (2 tiles x 4 K-chunks = 32 VGPR) ----
  half8 win[2][4];
#pragma unroll
  for (int tt = 0; tt < 2; ++tt)
#pragma unroll
    for (int kk = 0; kk < 4; ++kk)
      win[tt][kk] = f8_to_h8(Win + (size_t)(cw + tt*16 + lr) * NIN + kk*32 + lq*8);

  // ---- VGPR-resident Wout frags (1 tile x 8 K-chunks = 32 VGPR) ----
  half8 wo[8];
#pragma unroll
  for (int i = 0; i < 8; ++i)
    wo[i] = f8_to_h8(Wout + (size_t)(oj + tw*16 + lr) * NHID + (kh*8 + i)*32 + lq*8);

  const float binv0 = bin[cw + lr];
  const float binv1 = bin[cw + 16 + lr];
  const float bo    = bout[oj + tw*16 + lr];

  // ---- GLIFR state: 2 tiles x 4 rows per thread ----
  float v[8], a0[8], a1[8], sp[8];
#pragma unroll
  for (int i = 0; i < 8; ++i) { v[i] = 0.f; a0[i] = 0.f; a1[i] = 0.f; sp[i] = 0.f; }

  floatx4 rop;  // readout partial carried one step (waves 0,1)
  rop[0] = rop[1] = rop[2] = rop[3] = 0.f;

  const float C_VI = (float)(0.05 * 0.2 * (0.1 + 1.0 / 512.0));  // DT*K_M*R_HID

#pragma unroll 1
  for (int t = 0; t <= T_STEPS; ++t) {
    // ---- issue X loads early; they drain during the barrier wait ----
    floatx4 xlo[4], xhi[4];
    if (t < T_STEPS) {
      const float* xt = X + ((size_t)t * BATCH + m0 + lr) * NIN + lq * 8;
#pragma unroll
      for (int kk = 0; kk < 4; ++kk) {
        xlo[kk] = *(const floatx4*)(xt + kk * 32);
        xhi[kk] = *(const floatx4*)(xt + kk * 32 + 4);
      }
    }

    // ---- cluster barrier #t: s_{t-1} slices globally visible ----
    __syncthreads();                       // drains this block's ex stores
    if (tid == 0) {
      __threadfence();                     // release (L2 writeback)
      atomicAdd(cnt, 1u);                  // device scope
      const unsigned int tgt = (unsigned int)CLUSZ * (unsigned int)(t + 1);
      while (__hip_atomic_load(cnt, __ATOMIC_RELAXED, __HIP_MEMORY_SCOPE_AGENT) < tgt)
        __builtin_amdgcn_s_sleep(2);
    }
    __syncthreads();
    __threadfence();                       // acquire (invalidate stale L2)

    // ---- load s_{t-1} A-frags (16 x 16 B per lane, linear) ----
    const _Float16* sprev = ex + (size_t)(t & 1) * 131072 + (size_t)bi * 8192;
    half8 sfr[16];
#pragma unroll
    for (int kk = 0; kk < 16; ++kk)
      sfr[kk] = *(const half8*)(sprev + kk * 512 + l * 8);

    // ---- finalize out[t-2]: own partial + partner partial (written t-1) ----
    if (t >= 2 && w < 2) {
      floatx4 pp = *(const floatx4*)(smem + PBUF + ((t - 1) & 1) * 2048 + tw * 1024 + l * 16);
      float* op = out + ((size_t)(t - 2) * BATCH + m0 + lq * 4) * NOUT + oj + tw * 16 + lr;
#pragma unroll
      for (int r = 0; r < 4; ++r) op[(size_t)r * NOUT] = rop[r] + pp[r] + bo;
    }

    // ---- readout split-K partial for out[t-1] (off critical path) ----
    if (t >= 1) {
      floatx4 rp;
      rp[0] = rp[1] = rp[2] = rp[3] = 0.f;
#pragma unroll
      for (int i = 0; i < 8; ++i)
        rp = __builtin_amdgcn_mfma_f32_16x16x32_f16(sfr[kh*8 + i], wo[i], rp, 0, 0, 0);
      if (w >= 2) *(floatx4*)(smem + PBUF + (t & 1) * 2048 + tw * 1024 + l * 16) = rp;
      else        rop = rp;
    }

    // ---- recurrence + input projection + GLIFR pointwise -> s_t ----
    if (t < T_STEPS) {
      floatx4 acc[2];
      acc[0][0] = acc[0][1] = acc[0][2] = acc[0][3] = binv0;
      acc[1][0] = acc[1][1] = acc[1][2] = acc[1][3] = binv1;
#pragma unroll
      for (int kk = 0; kk < 16; ++kk) {
#pragma unroll
        for (int tt = 0; tt < 2; ++tt) {
          half8 wb = *(const half8*)(smem + (((w*2 + tt)*16 + kk) * 64 + l) * 16);
          acc[tt] = __builtin_amdgcn_mfma_f32_16x16x32_f16(sfr[kk], wb, acc[tt], 0, 0, 0);
        }
      }
#pragma unroll
      for (int kk = 0; kk < 4; ++kk) {
        half8 xa;
#pragma unroll
        for (int i = 0; i < 4; ++i) {
          xa[i]     = (_Float16)xlo[kk][i];
          xa[i + 4] = (_Float16)xhi[kk][i];
        }
#pragma unroll
        for (int tt = 0; tt < 2; ++tt)
          xa, acc[tt] = __builtin_amdgcn_mfma_f32_16x16x32_f16(xa, win[tt][kk], acc[tt], 0, 0, 0);
      }

      _Float16* scur = ex + (size_t)((t + 1) & 1) * 131072 + (size_t)bi * 8192;
#pragma unroll
      for (int tt = 0; tt < 2; ++tt)
#pragma unroll
        for (int r = 0; r < 4; ++r) {
          const int i = tt*4 + r;
          const float y  = 0.5f * acc[tt][r];                 // avg of 2 inputs
          a0[i] = a0[i] * 0.85f - 0.05f * sp[i];              // 1-DT*3,  -DT
          a1[i] = a1[i] * -0.5f - 0.05f * sp[i];              // 1-DT*30, -DT
          const float it = y + a0[i] + a1[i] + 700.0f;        // + I0
          v[i] = v[i] * 0.99f * (1.0f - 0.05f * sp[i]) + C_VI * it;
          const float s = 20.0f / (1.0f + __expf(-0.02f * v[i]));  // 20*sigmoid(v/50)
          sp[i] = s;
          // scatter into A-frag order: frag fk = hj*4+w, k_off = tt*16+lr
          const int koff  = tt*16 + lr;
          const int lane2 = (lq*4 + r) + 16*(koff >> 3);
          scur[(hj*4 + w)*512 + lane2*8 + (koff & 7)] = (_Float16)s;
        }
    }
  }

  // ---- epilogue: finalize out[T-1] (partials written at t = T_STEPS) ----
  __syncthreads();
  if (w < 2) {
    floatx4 pp = *(const floatx4*)(smem + PBUF + (T_STEPS & 1) * 2048 + tw * 1024 + l * 16);
    float* op = out + ((size_t)(T_STEPS - 1) * BATCH + m0 + lq * 4) * NOUT + oj + tw * 16 + lr;
#pragma unroll
    for (int r = 0; r < 4; ++r) op[(size_t)r * NOUT] = rop[r] + pp[r] + bo;
  }
}

extern "C" void kernel_launch(void* const* d_in, const int* in_sizes, int n_in,
                              void* d_out, int out_size, void* d_ws, size_t ws_size,
                              hipStream_t stream) {
  const float* X    = (const float*)d_in[0];
  const float* Win  = (const float*)d_in[1];
  const float* bin  = (const float*)d_in[2];
  const float* Wrec = (const float*)d_in[3];
  const float* Wout = (const float*)d_in[4];
  const float* bout = (const float*)d_in[5];
  float* out = (float*)d_out;
  char* ws = (char*)d_ws;

  hipLaunchKernelGGL(init_ws_kernel, dim3(128), dim3(256), 0, stream, ws);
  hipLaunchKernelGGL(bnn_cluster_kernel, dim3(NCLU * HGRP), dim3(256), 0, stream,
                     X, Win, bin, Wrec, Wout, bout, out, ws);
}

// Round 5
// 8338.622 us; speedup vs baseline: 2.0662x; 1.1076x over previous
//
#include <hip/hip_runtime.h>

#define T_STEPS 1000
#define BATCH   256
#define NIN     128
#define NHID    512
#define NOUT    128
#define ROWS    16    // batch rows per cluster
#define NCLU    16    // clusters (batch groups)

typedef _Float16 half8   __attribute__((ext_vector_type(8)));
typedef float    floatx4 __attribute__((ext_vector_type(4)));
typedef unsigned long long u64;

__device__ __forceinline__ half8 f8_to_h8(const float* __restrict__ p) {
  floatx4 lo = *(const floatx4*)p;
  floatx4 hi = *(const floatx4*)(p + 4);
  half8 r;
#pragma unroll
  for (int i = 0; i < 4; ++i) { r[i] = (_Float16)lo[i]; r[i + 4] = (_Float16)hi[i]; }
  return r;
}

// ---------------------------------------------------------------------------
// Workspace (557 056 B total), ALL cross-block data via relaxed agent-scope
// atomics (sc-flagged, served at the coherence point; no threadfence/wbl2/inv
// anywhere). No counters, no spin-on-atomicAdd, no s_sleep.
//   [0, 32768)      epoch flags, u32 @ 64 B stride: ((p*16+bi)*16+f)*64.
//                   flag value = epoch of the s published in (slot p, frag f).
//   [32768, +512K)  s data: slot p @ +p*262144, cluster bi @ +bi*16384,
//                   frag f @ +f*1024, lane l bytes [l*16, l*16+16).
// A-frag semantics (mfma_f32_16x16x32_f16): lane l holds
// s[row=l&15][k=(l>>4)*8+j], j=0..7. Frag kk covers hidden cols [kk*32,+32).
// Epochs: s_t published with epoch t+1 into slot (t+1)&1. Consumer at step t
// reads slot t&1 expecting epoch >= t (t=0 trivially satisfied by zeros).
// ---------------------------------------------------------------------------
#define DATA_OFF 32768

__global__ void init_ws_kernel(char* __restrict__ ws) {
  size_t idx = (size_t)blockIdx.x * blockDim.x + threadIdx.x;  // 136*256 = 34816
  ((int4*)ws)[idx] = make_int4(0, 0, 0, 0);                    // 557 056 B
}

// LDS map: [0,131072) Wrec B-frags ((w*2+tt)*16+kk)*1024 + l*16
//          [131072,135168) readout split-K partials (parity double-buffered)
//          [135168,139264) per-wave transpose stage (wave-local only)
#define PBUF  131072
#define STAGE 135168

__global__ __launch_bounds__(256, 1) void bnn_flag_kernel(
    const float* __restrict__ X,     // [T,B,NIN]
    const float* __restrict__ Win,   // [NHID,NIN]
    const float* __restrict__ bin,   // [NHID]
    const float* __restrict__ Wrec,  // [NHID,NHID]
    const float* __restrict__ Wout,  // [NOUT,NHID]
    const float* __restrict__ bout,  // [NOUT]
    float* __restrict__ out,         // [T,B,NOUT]
    char* __restrict__ ws)
{
  __shared__ __attribute__((aligned(16))) char smem[139264];
  const int tid = threadIdx.x;
  const int l   = tid & 63;
  const int w   = tid >> 6;          // wave 0..3
  const int lr  = l & 15;
  const int lq  = l >> 4;
  const int bi  = blockIdx.x & 15;   // cluster (batch group)
  const int hj  = blockIdx.x >> 4;   // hidden group (4 per cluster)
  const int m0  = bi * ROWS;
  const int cw  = hj * 128 + w * 32; // this wave's 2 hidden tiles
  const int oj  = hj * 32;           // block's 32 out cols
  const int tw  = w & 1;             // readout tile (0/1)
  const int kh  = w >> 1;            // readout K-half (0/1)
  const int myf = hj * 4 + w;        // this wave's frag id (0..15)

  unsigned* flags = (unsigned*)ws;

  // ---- one-time: Wrec B-frags -> LDS (fp16, fragment order) ----
#pragma unroll
  for (int tt = 0; tt < 2; ++tt)
#pragma unroll
    for (int kk = 0; kk < 16; ++kk) {
      half8 v = f8_to_h8(Wrec + (size_t)(cw + tt*16 + lr) * NHID + kk*32 + lq*8);
      *(half8*)(smem + (((w*2 + tt)*16 + kk) * 64 + l) * 16) = v;
    }

  // ---- VGPR-resident Win frags (2 tiles x 4 K-chunks) ----
  half8 win[2][4];
#pragma unroll
  for (int tt = 0; tt < 2; ++tt)
#pragma unroll
    for (int kk = 0; kk < 4; ++kk)
      win[tt][kk] = f8_to_h8(Win + (size_t)(cw + tt*16 + lr) * NIN + kk*32 + lq*8);

  // ---- VGPR-resident Wout frags (1 tile x 8 K-chunks, split-K by kh) ----
  half8 wo[8];
#pragma unroll
  for (int i = 0; i < 8; ++i)
    wo[i] = f8_to_h8(Wout + (size_t)(oj + tw*16 + lr) * NHID + (kh*8 + i)*32 + lq*8);

  const float binv0 = bin[cw + lr];
  const float binv1 = bin[cw + 16 + lr];
  const float bo    = bout[oj + tw*16 + lr];

  // ---- GLIFR state: 2 tiles x 4 rows per thread ----
  float v[8], a0[8], a1[8], sp[8];
#pragma unroll
  for (int i = 0; i < 8; ++i) { v[i] = 0.f; a0[i] = 0.f; a1[i] = 0.f; sp[i] = 0.f; }

  floatx4 rop;  // readout partial carried one step (waves 0,1)
  rop[0] = rop[1] = rop[2] = rop[3] = 0.f;

  const float C_VI = (float)(0.05 * 0.2 * (0.1 + 1.0 / 512.0));  // DT*K_M*R_HID

  __syncthreads();   // Wrec LDS visible

#pragma unroll 1
  for (int t = 0; t <= T_STEPS; ++t) {
    // ---- X_t loads issue first (HBM latency overlaps poll + exchange) ----
    floatx4 xlo[4], xhi[4];
    if (t < T_STEPS) {
      const float* xt = X + ((size_t)t * BATCH + m0 + lr) * NIN + lq * 8;
#pragma unroll
      for (int kk = 0; kk < 4; ++kk) {
        xlo[kk] = *(const floatx4*)(xt + kk * 32);
        xhi[kk] = *(const floatx4*)(xt + kk * 32 + 4);
      }
    }

    // ---- poll the 16 epoch flags of (slot t&1, cluster bi): lane f polls
    //      flag f; ballot until all >= t. Waits only on completed producer
    //      work -> deadlock-free by induction. ----
    if (t > 0) {
      const unsigned* flg = flags + (size_t)((t & 1) * 16 + bi) * 256;  // 16 flags @ 16 u32
      u64 rdy;
      do {
        unsigned fv = 0xFFFFFFFFu;
        if (l < 16)
          fv = __hip_atomic_load(flg + l * 16, __ATOMIC_RELAXED, __HIP_MEMORY_SCOPE_AGENT);
        rdy = __ballot(fv >= (unsigned)t);
      } while (rdy != 0xFFFFFFFFFFFFFFFFull);
    }
    __builtin_amdgcn_sched_barrier(0);   // frag loads must not hoist above poll

    // ---- all 16 s_{t-1} frags from the coherence point (32 u64 in flight) ----
    const u64* dq = (const u64*)(ws + DATA_OFF + (size_t)(t & 1) * 262144
                                 + (size_t)bi * 16384);
    half8 sfr[16];
#pragma unroll
    for (int kk = 0; kk < 16; ++kk) {
      union { u64 u[2]; half8 h; } cv;
      cv.u[0] = __hip_atomic_load(dq + kk*128 + l*2,     __ATOMIC_RELAXED, __HIP_MEMORY_SCOPE_AGENT);
      cv.u[1] = __hip_atomic_load(dq + kk*128 + l*2 + 1, __ATOMIC_RELAXED, __HIP_MEMORY_SCOPE_AGENT);
      sfr[kk] = cv.h;
    }

    // ---- finalize out[t-2]: own partial + partner partial (written t-1) ----
    if (t >= 2 && w < 2) {
      floatx4 pp = *(const floatx4*)(smem + PBUF + ((t - 1) & 1) * 2048 + tw * 1024 + l * 16);
      float* op = out + ((size_t)(t - 2) * BATCH + m0 + lq * 4) * NOUT + oj + tw * 16 + lr;
#pragma unroll
      for (int r = 0; r < 4; ++r) op[(size_t)r * NOUT] = rop[r] + pp[r] + bo;
    }

    // ---- readout split-K partial for out[t-1] ----
    if (t >= 1) {
      floatx4 rp;
      rp[0] = rp[1] = rp[2] = rp[3] = 0.f;
#pragma unroll
      for (int i = 0; i < 8; ++i)
        rp = __builtin_amdgcn_mfma_f32_16x16x32_f16(sfr[kh*8 + i], wo[i], rp, 0, 0, 0);
      if (w >= 2) *(floatx4*)(smem + PBUF + (t & 1) * 2048 + tw * 1024 + l * 16) = rp;
      else        rop = rp;
    }

    // ---- recurrence + input projection + GLIFR pointwise -> publish s_t ----
    if (t < T_STEPS) {
      floatx4 acc[2];
      acc[0][0] = acc[0][1] = acc[0][2] = acc[0][3] = binv0;
      acc[1][0] = acc[1][1] = acc[1][2] = acc[1][3] = binv1;
#pragma unroll
      for (int kk = 0; kk < 16; ++kk) {
#pragma unroll
        for (int tt = 0; tt < 2; ++tt) {
          half8 wb = *(const half8*)(smem + (((w*2 + tt)*16 + kk) * 64 + l) * 16);
          acc[tt] = __builtin_amdgcn_mfma_f32_16x16x32_f16(sfr[kk], wb, acc[tt], 0, 0, 0);
        }
      }
#pragma unroll
      for (int kk = 0; kk < 4; ++kk) {
        half8 xa;
#pragma unroll
        for (int i = 0; i < 4; ++i) {
          xa[i]     = (_Float16)xlo[kk][i];
          xa[i + 4] = (_Float16)xhi[kk][i];
        }
#pragma unroll
        for (int tt = 0; tt < 2; ++tt)
          acc[tt] = __builtin_amdgcn_mfma_f32_16x16x32_f16(xa, win[tt][kk], acc[tt], 0, 0, 0);
      }

      // pointwise update; scatter into the wave-local transpose stage
#pragma unroll
      for (int tt = 0; tt < 2; ++tt)
#pragma unroll
        for (int r = 0; r < 4; ++r) {
          const int i = tt*4 + r;
          const float y  = 0.5f * acc[tt][r];                 // avg of 2 inputs
          a0[i] = a0[i] * 0.85f - 0.05f * sp[i];              // 1-DT*3,  -DT
          a1[i] = a1[i] * -0.5f - 0.05f * sp[i];              // 1-DT*30, -DT
          const float it = y + a0[i] + a1[i] + 700.0f;        // + I0
          v[i] = v[i] * 0.99f * (1.0f - 0.05f * sp[i]) + C_VI * it;
          const float s = 20.0f / (1.0f + __expf(-0.02f * v[i]));  // 20*sigmoid(v/50)
          sp[i] = s;
          const int koff  = tt*16 + lr;                       // col within frag
          const int lane2 = (lq*4 + r) + 16*(koff >> 3);      // dest lane
          *(_Float16*)(smem + STAGE + w*1024 + lane2*16 + (koff & 7)*2) = (_Float16)s;
        }

      // wave-local readback (A-frag layout) -> sc-publish -> drain -> flag
      asm volatile("s_waitcnt lgkmcnt(0)" ::: "memory");
      __builtin_amdgcn_sched_barrier(0);
      u64 s0 = *(const u64*)(smem + STAGE + w*1024 + l*16);
      u64 s1 = *(const u64*)(smem + STAGE + w*1024 + l*16 + 8);
      u64* dst = (u64*)(ws + DATA_OFF + (size_t)((t + 1) & 1) * 262144
                        + (size_t)bi * 16384) + (size_t)myf * 128 + l * 2;
      __hip_atomic_store(dst,     s0, __ATOMIC_RELAXED, __HIP_MEMORY_SCOPE_AGENT);
      __hip_atomic_store(dst + 1, s1, __ATOMIC_RELAXED, __HIP_MEMORY_SCOPE_AGENT);
      asm volatile("s_waitcnt vmcnt(0)" ::: "memory");   // data at coherence point
      __builtin_amdgcn_sched_barrier(0);
      if (l == 0) {
        unsigned* fl = flags + (size_t)(((t + 1) & 1) * 16 + bi) * 256 + (size_t)myf * 16;
        __hip_atomic_store(fl, (unsigned)(t + 1), __ATOMIC_RELAXED, __HIP_MEMORY_SCOPE_AGENT);
      }
    }

    __syncthreads();   // orders PBUF write(t) -> read(t+1); keeps waves together
  }

  // ---- epilogue: finalize out[T-1] (partials written at t = T_STEPS) ----
  if (w < 2) {
    floatx4 pp = *(const floatx4*)(smem + PBUF + (T_STEPS & 1) * 2048 + tw * 1024 + l * 16);
    float* op = out + ((size_t)(T_STEPS - 1) * BATCH + m0 + lq * 4) * NOUT + oj + tw * 16 + lr;
#pragma unroll
    for (int r = 0; r < 4; ++r) op[(size_t)r * NOUT] = rop[r] + pp[r] + bo;
  }
}

extern "C" void kernel_launch(void* const* d_in, const int* in_sizes, int n_in,
                              void* d_out, int out_size, void* d_ws, size_t ws_size,
                              hipStream_t stream) {
  const float* X    = (const float*)d_in[0];
  const float* Win  = (const float*)d_in[1];
  const float* bin  = (const float*)d_in[2];
  const float* Wrec = (const float*)d_in[3];
  const float* Wout = (const float*)d_in[4];
  const float* bout = (const float*)d_in[5];
  float* out = (float*)d_out;
  char* ws = (char*)d_ws;

  hipLaunchKernelGGL(init_ws_kernel, dim3(136), dim3(256), 0, stream, ws);
  hipLaunchKernelGGL(bnn_flag_kernel, dim3(64), dim3(256), 0, stream,
                     X, Win, bin, Wrec, Wout, bout, out, ws);
}